// Round 4
// baseline (384.562 us; speedup 1.0000x reference)
//
#include <hip/hip_runtime.h>
#include <hip/hip_fp16.h>

// Problem constants (fixed by setup_inputs): B=1, KVH=8, D=128, S=8192
#define HH 8
#define DD 128
#define SS 8192

// ---------------- attn mask fill: out[r][c] = (c>r ? -128 : 0) * mask ----------------
// One 32 KB row per block; each wave iteration stores 64 consecutive float4 = 1 KB.
// Plain stores (no NT) — the harness fill kernel proves this config sustains 6.4 TB/s.
__global__ __launch_bounds__(256) void attn_kernel(const int* __restrict__ maskp,
                                                   float* __restrict__ out) {
    const float hi = (float)(-128 * (*maskp));
    const int r = blockIdx.x;                       // row index, 0..8191
    float4* row = (float4*)out + (size_t)r * (SS / 4);
    const int t = threadIdx.x;
#pragma unroll
    for (int k = 0; k < 8; ++k) {
        const int f4 = k * 256 + t;                 // float4 index in row, 0..2047
        const int c = f4 << 2;
        float4 v;
        v.x = (c     > r) ? hi : 0.0f;
        v.y = (c + 1 > r) ? hi : 0.0f;
        v.z = (c + 2 > r) ? hi : 0.0f;
        v.w = (c + 3 > r) ? hi : 0.0f;
        row[f4] = v;
    }
}

// ---------------- keys: (H, D, S), quantize over D (stride 32 KB) ----------------
// Tile = 256 s x 128 d per block (512 threads). Wave = 64 lanes x float4 ->
// 1 KB contiguous per load/store instruction. Data held in 16 float4 registers
// between the min/max pass and the pack pass; reciprocal hoisted to 1/column.
__global__ __launch_bounds__(512) void keys_kernel(const float* __restrict__ keys,
                                                   float* __restrict__ kp,
                                                   float* __restrict__ ks,
                                                   float* __restrict__ kb) {
    const int h   = blockIdx.x >> 5;
    const int s04 = (blockIdx.x & 31) << 6;  // float4 offset of s-tile (64 f4 = 256 s)
    const int l   = threadIdx.x & 63;
    const int w   = threadIdx.x >> 6;        // 0..7, owns d rows w*16 .. w*16+15
    const float4* k4 = (const float4*)keys;

    __shared__ float4 smin[8][64], smax[8][64];
    __shared__ float4 sbias[64], sinv[64];

    float4 val[16];
    float4 mn4 = make_float4(3e38f, 3e38f, 3e38f, 3e38f);
    float4 mx4 = make_float4(-3e38f, -3e38f, -3e38f, -3e38f);
#pragma unroll
    for (int j = 0; j < 16; ++j) {
        float4 v = k4[(size_t)(h * DD + w * 16 + j) * (SS / 4) + s04 + l];
        val[j] = v;
        mn4.x = fminf(mn4.x, v.x); mn4.y = fminf(mn4.y, v.y);
        mn4.z = fminf(mn4.z, v.z); mn4.w = fminf(mn4.w, v.w);
        mx4.x = fmaxf(mx4.x, v.x); mx4.y = fmaxf(mx4.y, v.y);
        mx4.z = fmaxf(mx4.z, v.z); mx4.w = fmaxf(mx4.w, v.w);
    }
    smin[w][l] = mn4;
    smax[w][l] = mx4;
    __syncthreads();
    if (w == 0) {
        float4 m = smin[0][l], M = smax[0][l];
#pragma unroll
        for (int i = 1; i < 8; ++i) {
            float4 a = smin[i][l], b = smax[i][l];
            m.x = fminf(m.x, a.x); m.y = fminf(m.y, a.y);
            m.z = fminf(m.z, a.z); m.w = fminf(m.w, a.w);
            M.x = fmaxf(M.x, b.x); M.y = fmaxf(M.y, b.y);
            M.z = fmaxf(M.z, b.z); M.w = fmaxf(M.w, b.w);
        }
        float4 sc;  // fp32 scale, matches (max-min)*(1/QMAX) before astype
        sc.x = (M.x - m.x) * (1.0f / 255.0f); sc.y = (M.y - m.y) * (1.0f / 255.0f);
        sc.z = (M.z - m.z) * (1.0f / 255.0f); sc.w = (M.w - m.w) * (1.0f / 255.0f);
        float4 kso, kbo;  // astype(f16) round-trip, RNE
        kso.x = __half2float(__float2half(sc.x)); kso.y = __half2float(__float2half(sc.y));
        kso.z = __half2float(__float2half(sc.z)); kso.w = __half2float(__float2half(sc.w));
        kbo.x = __half2float(__float2half(m.x)); kbo.y = __half2float(__float2half(m.y));
        kbo.z = __half2float(__float2half(m.z)); kbo.w = __half2float(__float2half(m.w));
        ((float4*)ks)[h * (SS / 4) + s04 + l] = kso;
        ((float4*)kb)[h * (SS / 4) + s04 + l] = kbo;
        float4 inv;  // hoist reciprocal: 1 div/column instead of 1 div/element
        inv.x = 1.0f / sc.x; inv.y = 1.0f / sc.y;
        inv.z = 1.0f / sc.z; inv.w = 1.0f / sc.w;
        sbias[l] = m;
        sinv[l]  = inv;
    }
    __syncthreads();
    const float4 b4 = sbias[l];
    const float4 i4 = sinv[l];
    float4* o4 = (float4*)kp;
#pragma unroll
    for (int j = 0; j < 16; ++j) {
        float4 o;
        o.x = rintf((val[j].x - b4.x) * i4.x);
        o.y = rintf((val[j].y - b4.y) * i4.y);
        o.z = rintf((val[j].z - b4.z) * i4.z);
        o.w = rintf((val[j].w - b4.w) * i4.w);
        o4[(size_t)(h * DD + w * 16 + j) * (SS / 4) + s04 + l] = o;
    }
}

// ---------------- values: (H, S, D), quantize over contiguous D=128 ----------------
// 32 lanes per row, one float4 each; per wave the 2 rows are consecutive ->
// 1 KB contiguous per load/store. Butterfly __shfl_xor stays in the 32-lane group.
__global__ __launch_bounds__(256) void vals_kernel(const float* __restrict__ vals,
                                                   float* __restrict__ vp,
                                                   float* __restrict__ vs,
                                                   float* __restrict__ vb) {
    const int d4 = threadIdx.x & 31;          // float4 index within row
    const int rr = threadIdx.x >> 5;          // 0..7 rows per block
    const int R  = blockIdx.x * 8 + rr;       // flat row = h*8192 + s

    const float4 v = ((const float4*)vals)[R * 32 + d4];
    float mn = fminf(fminf(v.x, v.y), fminf(v.z, v.w));
    float mx = fmaxf(fmaxf(v.x, v.y), fmaxf(v.z, v.w));
#pragma unroll
    for (int off = 16; off >= 1; off >>= 1) {
        mn = fminf(mn, __shfl_xor(mn, off));
        mx = fmaxf(mx, __shfl_xor(mx, off));
    }
    const float scale = (mx - mn) * (1.0f / 255.0f);
    const float inv = 1.0f / scale;
    if (d4 == 0) {
        // v_scale swapaxes(-1,-2) is a flat no-op: both flat [h][s] = [R]
        vs[R] = __half2float(__float2half(scale));
        vb[R] = __half2float(__float2half(mn));
    }
    float4 o;
    o.x = rintf((v.x - mn) * inv);
    o.y = rintf((v.y - mn) * inv);
    o.z = rintf((v.z - mn) * inv);
    o.w = rintf((v.w - mn) * inv);
    ((float4*)vp)[R * 32 + d4] = o;
}

extern "C" void kernel_launch(void* const* d_in, const int* in_sizes, int n_in,
                              void* d_out, int out_size, void* d_ws, size_t ws_size,
                              hipStream_t stream) {
    const float* keys  = (const float*)d_in[0];
    const float* vals  = (const float*)d_in[1];
    const int*   maskp = (const int*)d_in[2];

    float* out  = (float*)d_out;
    float* attn = out;              // 8192*8192    = 67108864
    float* kp   = attn + 67108864;  // 8*128*8192   =  8388608
    float* ks   = kp   + 8388608;   // 8*8192       =    65536
    float* kb   = ks   + 65536;
    float* vp   = kb   + 65536;     //                 8388608
    float* vs   = vp   + 8388608;
    float* vbv  = vs   + 65536;

    // Readers first, big pure-writer last; sequential homogeneous phases avoid
    // HBM read/write-mixing turnaround losses (R3 fusion was net negative).
    keys_kernel<<<dim3(HH * (SS / 256)), dim3(512), 0, stream>>>(keys, kp, ks, kb);
    vals_kernel<<<dim3(HH * SS / 8), dim3(256), 0, stream>>>(vals, vp, vs, vbv);
    attn_kernel<<<dim3(SS), dim3(256), 0, stream>>>(maskp, attn);
}